// Round 6
// baseline (253.213 us; speedup 1.0000x reference)
//
#include <hip/hip_runtime.h>
#include <hip/hip_bf16.h>
#include <stdint.h>

typedef unsigned short u16;
typedef __attribute__((ext_vector_type(8))) short short8;   // 8 x bf16 (4 VGPRs) MFMA A/B frag
typedef __attribute__((ext_vector_type(4))) float floatx4;  // MFMA C/D frag

#define BATCH 4
#define SEQ   2048
#define DIM   1024

__device__ inline u16 f2bf(float f) {
  union { float f; uint32_t u; } v; v.f = f;
  uint32_t r = v.u + 0x7fffu + ((v.u >> 16) & 1u);  // RNE
  return (u16)(r >> 16);
}

// async global->LDS, 16B per lane; LDS dest is wave-uniform base (+lane*16 by HW)
__device__ inline void gload_lds16(const u16* g, u16* l) {
  __builtin_amdgcn_global_load_lds((const __attribute__((address_space(1))) uint32_t*)g,
                                   (__attribute__((address_space(3))) uint32_t*)l,
                                   16, 0, 0);
}

// ---------------- elementwise fp32 -> bf16 (+ zero the rowsum buffer) ----------------
__global__ __launch_bounds__(256) void cvt_x(const float* __restrict__ in,
                                             u16* __restrict__ out,
                                             float* __restrict__ lsum) {
  size_t i = ((size_t)blockIdx.x * 256 + threadIdx.x) * 4;
  float4 v = *(const float4*)(in + i);
  ushort4 o;
  o.x = f2bf(v.x); o.y = f2bf(v.y); o.z = f2bf(v.z); o.w = f2bf(v.w);
  *(ushort4*)(out + i) = o;
  if (blockIdx.x < 8) {  // zero 8192 floats of lsum
    float4 z = {0.f, 0.f, 0.f, 0.f};
    *(float4*)(lsum + (size_t)blockIdx.x * 1024 + threadIdx.x * 4) = z;
  }
}

// ---------------- W[d][h] fp32 -> Wt[h][d] bf16 (3 weights via z) ----------------
__global__ __launch_bounds__(256) void transpose_w(const float* __restrict__ Wq,
                                                   const float* __restrict__ Wk,
                                                   const float* __restrict__ Wv,
                                                   u16* __restrict__ out) {
  const float* W = (blockIdx.z == 0) ? Wq : (blockIdx.z == 1) ? Wk : Wv;
  u16* o = out + (size_t)blockIdx.z * (1u << 20);
  __shared__ u16 tile[32][33];
  int c0 = blockIdx.x * 32, r0 = blockIdx.y * 32;
  int tx = threadIdx.x & 31, ty = threadIdx.x >> 5;  // ty 0..7
#pragma unroll
  for (int p = 0; p < 4; ++p)
    tile[p * 8 + ty][tx] = f2bf(W[(size_t)(r0 + p * 8 + ty) * DIM + c0 + tx]);
  __syncthreads();
#pragma unroll
  for (int p = 0; p < 4; ++p)
    o[(size_t)(c0 + p * 8 + ty) * DIM + r0 + tx] = tile[tx][p * 8 + ty];
}

// ---------------- pack bq,bk,bv contiguously ----------------
__global__ void gather_bias(const float* __restrict__ bq, const float* __restrict__ bk,
                            const float* __restrict__ bv, float* __restrict__ out) {
  int i = blockIdx.x * 256 + threadIdx.x;  // 0..1023
  const float* s = (blockIdx.y == 0) ? bq : (blockIdx.y == 1) ? bk : bv;
  out[blockIdx.y * 1024 + i] = s[i];
}

// ---------------- bf16 GEMM, BK=64 (two 32-k slabs per barrier pair) ----------------
// C[m][n] = sum_k A[m][k] * Bt[n][k].  Block tile TM x 128.
// TM=128: 4 waves of 64x64 (acc 4x4), 3 blocks/CU.  Use when B streams (needs
//   cross-block overlap to hide barrier drain — TM=256 regressed QK^T 47->74 us).
// TM=256: 4 waves of 128x64 (acc 8x4), 2 blocks/CU.  OK when B is tiny/L2-resident (QKV).
// EPI 0: (acc+bias[col])*zscale (z==0 -> 1/32), bf16 out.
// EPI 1: exp(acc), bf16 out, atomicAdd per-row sums into lsum.
// EPI 2: acc * (1/lsum[row]), fp32 out.
// EPI 3: acc + bias[row] (V bias), bf16, column-demuxed store into Vt[b][h][s].
// SWIZ 0: grid(M/TM,8,z): mt=x, nt=y   (xcd = mt%8 -> A-stripe per XCD)
// SWIZ 1: grid(256,1,z): mt 16, nt 16  (4m x 8n super-tile per XCD, TM=128)
// SWIZ 2: grid(128,1,z): mt 16, nt 8   (4m x 4n super-tile per XCD, TM=128)
// SWIZ 3: grid(64,8,1): nt=x, mt=y     (xcd = nt%8 -> B-stripe per XCD)
// SWIZ 4: grid(128,1,z): mt 8, nt 16   (TM=256: 4m x 4n per XCD)
template <int EPI, int SWIZ, int TM>
__global__ __launch_bounds__(256, (TM == 256) ? 2 : 3)
void gemm_bt(const u16* __restrict__ A, const u16* __restrict__ Bt,
             void* __restrict__ Cv, const float* __restrict__ bias,
             float* __restrict__ lsum, int M, int N, int K,
             size_t sA, size_t sB, size_t sC) {
  constexpr int MI = TM / 32;          // acc rows of 16 per wave (4 or 8)
  constexpr int AS = TM / 64;          // A staging insts per wave per slab (2 or 4)
  __shared__ u16 ldsA[TM * 64];        // two slabs of TM x 32
  __shared__ u16 ldsB[128 * 64];
  const int lane = threadIdx.x & 63;
  const int wave = threadIdx.x >> 6;

  int mt, nt;
  if (SWIZ == 0) {
    mt = blockIdx.x; nt = blockIdx.y;
  } else if (SWIZ == 1) {
    const int lin = blockIdx.x;            // 0..255
    const int c = lin & 7, j = lin >> 3;   // xcd-slot, index within slot
    mt = 4 * (c & 3) + (j & 3);            // 16 m-tiles
    nt = 8 * (c >> 2) + (j >> 2);          // 16 n-tiles
  } else if (SWIZ == 2) {
    const int lin = blockIdx.x;            // 0..127
    const int c = lin & 7, j = lin >> 3;
    mt = 4 * (c >> 1) + (j & 3);           // 16 m-tiles
    nt = 4 * (c & 1) + (j >> 2);           // 8 n-tiles
  } else if (SWIZ == 3) {
    nt = blockIdx.x; mt = blockIdx.y;
  } else {
    const int lin = blockIdx.x;            // 0..127
    const int c = lin & 7, j = lin >> 3;
    mt = 4 * (c & 1) + (j & 3);            // 8 m-tiles
    nt = 4 * (c >> 1) + (j >> 2);          // 16 n-tiles
  }

  const u16* Ab = A + sA * blockIdx.z + (size_t)mt * TM * K;
  const u16* Bb = Bt + sB * blockIdx.z + (size_t)nt * 128 * K;

  // staging: wave w covers A rows [w*TM/4,...), B rows [w*32,...); insts of 16 rows.
  const int sr = lane >> 2;          // row within 16-row group
  const int sc = (lane & 3) * 8;     // k-offset (elements), 16B chunks
  const u16* gA0 = Ab + (size_t)(wave * (TM / 4) + sr) * K + sc;
  const u16* gB0 = Bb + (size_t)(wave * 32 + sr) * K + sc;
  u16* lA0 = ldsA + wave * (TM / 4) * 32;   // per 16-row inst: +512 els
  u16* lB0 = ldsB + wave * 1024;
  constexpr int SLA = TM * 32;       // A slab1 offset (elements)
  constexpr int SLB = 4096;          // B slab1 offset

  // compute: waves 2x2; wave tile (TM/2) x 64
  const int wm = (wave >> 1) * (TM / 2);
  const int wn = (wave & 1) * 64;
  const int fr = lane & 15;
  const int fk = (lane >> 4) * 8;
  const u16* la = ldsA + (wm + fr) * 32 + fk;
  const u16* lb = ldsB + (wn + fr) * 32 + fk;

  floatx4 acc[MI][4] = {};

  for (int kt = 0; kt < K; kt += 64) {
    __syncthreads();
#pragma unroll
    for (int i = 0; i < AS; ++i) {
      gload_lds16(gA0 + kt + (size_t)(16 * i) * K, lA0 + i * 512);
      gload_lds16(gA0 + kt + 32 + (size_t)(16 * i) * K, lA0 + SLA + i * 512);
    }
#pragma unroll
    for (int i = 0; i < 2; ++i) {
      gload_lds16(gB0 + kt + (size_t)(16 * i) * K, lB0 + i * 512);
      gload_lds16(gB0 + kt + 32 + (size_t)(16 * i) * K, lB0 + SLB + i * 512);
    }
    __syncthreads();
#pragma unroll
    for (int ks = 0; ks < 2; ++ks) {
      short8 a[MI], b[4];
#pragma unroll
      for (int i = 0; i < MI; ++i)
        a[i] = *(const short8*)(la + ks * SLA + i * 512);
#pragma unroll
      for (int i = 0; i < 4; ++i)
        b[i] = *(const short8*)(lb + ks * SLB + i * 512);
#pragma unroll
      for (int mi = 0; mi < MI; ++mi)
#pragma unroll
        for (int ni = 0; ni < 4; ++ni)
          acc[mi][ni] = __builtin_amdgcn_mfma_f32_16x16x32_bf16(a[mi], b[ni], acc[mi][ni], 0, 0, 0);
    }
  }

  // epilogue: C/D layout col=lane&15, row=(lane>>4)*4+r
  const int er = (lane >> 4) * 4;
  const int ec = lane & 15;
  const int r0 = mt * TM + wm;
  const int c0 = nt * 128 + wn;

  if (EPI == 0) {
    u16* C = (u16*)Cv + sC * blockIdx.z;
    const float* bz = bias + blockIdx.z * 1024;
    const float zs = (blockIdx.z == 0) ? 0.03125f : 1.0f;  // fold 1/sqrt(1024) into Q
#pragma unroll
    for (int mi = 0; mi < MI; ++mi)
#pragma unroll
      for (int ni = 0; ni < 4; ++ni) {
        const int col = c0 + ni * 16 + ec;
        const float bb = bz[col];
#pragma unroll
        for (int r = 0; r < 4; ++r) {
          const int row = r0 + mi * 16 + er + r;
          C[(size_t)row * N + col] = f2bf((acc[mi][ni][r] + bb) * zs);
        }
      }
  } else if (EPI == 1) {
    // P~ = exp(s) (no max subtraction: |s| bounded, fp32-safe), row sums -> lsum.
    u16* C = (u16*)Cv + sC * blockIdx.z;
    float* lz = lsum + blockIdx.z * 2048;
#pragma unroll
    for (int mi = 0; mi < MI; ++mi) {
      float rs[4] = {0.f, 0.f, 0.f, 0.f};
#pragma unroll
      for (int ni = 0; ni < 4; ++ni) {
        const int col = c0 + ni * 16 + ec;
#pragma unroll
        for (int r = 0; r < 4; ++r) {
          const int row = r0 + mi * 16 + er + r;
          const float e = exp2f(acc[mi][ni][r] * 1.44269504088896340736f);
          C[(size_t)row * N + col] = f2bf(e);
          rs[r] += e;
        }
      }
#pragma unroll
      for (int o = 1; o < 16; o <<= 1)
#pragma unroll
        for (int r = 0; r < 4; ++r) rs[r] += __shfl_xor(rs[r], o);
      if ((lane & 15) == 0) {
#pragma unroll
        for (int r = 0; r < 4; ++r)
          atomicAdd(&lz[r0 + mi * 16 + er + r], rs[r]);
      }
    }
  } else if (EPI == 2) {
    float* C = (float*)Cv + sC * blockIdx.z;
    const float* lz = lsum + blockIdx.z * 2048;
#pragma unroll
    for (int mi = 0; mi < MI; ++mi) {
      float inv[4];
#pragma unroll
      for (int r = 0; r < 4; ++r) inv[r] = 1.0f / lz[r0 + mi * 16 + er + r];
#pragma unroll
      for (int ni = 0; ni < 4; ++ni) {
        const int col = c0 + ni * 16 + ec;
#pragma unroll
        for (int r = 0; r < 4; ++r) {
          const int row = r0 + mi * 16 + er + r;
          C[(size_t)row * N + col] = acc[mi][ni][r] * inv[r];
        }
      }
    }
  } else {
    // Vt[b][h][s]: rows m = h, cols n = global s (b = col>>11).
    u16* C = (u16*)Cv;
    const float* bz = bias + 2 * 1024;  // bv, indexed by row (=h)
#pragma unroll
    for (int mi = 0; mi < MI; ++mi) {
      float bb[4];
#pragma unroll
      for (int r = 0; r < 4; ++r) bb[r] = bz[r0 + mi * 16 + er + r];
#pragma unroll
      for (int ni = 0; ni < 4; ++ni) {
        const int col = c0 + ni * 16 + ec;
        const size_t base = (size_t)(col >> 11) * (1u << 21) + (col & 2047);
#pragma unroll
        for (int r = 0; r < 4; ++r) {
          const int row = r0 + mi * 16 + er + r;
          C[base + (size_t)row * 2048] = f2bf(acc[mi][ni][r] + bb[r]);
        }
      }
    }
  }
}

extern "C" void kernel_launch(void* const* d_in, const int* in_sizes, int n_in,
                              void* d_out, int out_size, void* d_ws, size_t ws_size,
                              hipStream_t stream) {
  const float* x  = (const float*)d_in[0];
  const float* Wq = (const float*)d_in[1];
  const float* bq = (const float*)d_in[2];
  const float* Wk = (const float*)d_in[3];
  const float* bk = (const float*)d_in[4];
  const float* Wv = (const float*)d_in[5];
  const float* bv = (const float*)d_in[6];
  float* out = (float*)d_out;

  char* ws = (char*)d_ws;
  const size_t MB = 1ull << 20;
  u16* Q    = (u16*)(ws + 0 * MB);    // [2][8192][1024] bf16: Q,K contiguous
  u16* Kb   = (u16*)(ws + 16 * MB);
  u16* Vt   = (u16*)(ws + 48 * MB);   // [4][1024][2048]
  u16* Xb   = (u16*)(ws + 64 * MB);   // [8192][1024]
  u16* Wt   = (u16*)(ws + 80 * MB);   // [3][1024][1024]
  float* bias = (float*)(ws + 86 * MB);  // [3][1024]
  float* lsum = (float*)(ws + 87 * MB);  // [4][2048] softmax denominators
  u16* P    = (u16*)(ws + 88 * MB);   // [4][2048][2048] exp(scores), ends 120MB
  (void)Kb; (void)ws_size; (void)in_sizes; (void)n_in; (void)out_size;

  // 1) x -> bf16 (+ zero lsum)
  cvt_x<<<8192, 256, 0, stream>>>(x, Xb, lsum);
  // 2) W -> Wt bf16
  transpose_w<<<dim3(32, 32, 3), 256, 0, stream>>>(Wq, Wk, Wv, Wt);
  // 3) biases contiguous
  gather_bias<<<dim3(4, 3, 1), 256, 0, stream>>>(bq, bk, bv, bias);
  // 4a) Q,K projection (Q pre-scaled by 1/32), z = q/k.  TM=256 (B=Wt is L2-resident).
  gemm_bt<0, 0, 256><<<dim3(32, 8, 2), 256, 0, stream>>>(
      Xb, Wt, Q, bias, nullptr, 8192, 1024, 1024,
      (size_t)0, (size_t)(1u << 20), (size_t)(8u << 20));
  // 4b) Vt = Wv^T x^T + bv (direct transposed V projection).  TM=128, B-stripe per XCD.
  gemm_bt<3, 3, 128><<<dim3(64, 8, 1), 256, 0, stream>>>(
      Wt + 2 * (1u << 20), Xb, Vt, bias, nullptr, 1024, 8192, 1024,
      (size_t)0, (size_t)0, (size_t)0);
  // 5) P~ = exp(Q K^T), row sums -> lsum.  TM=128 (B=K streams; needs 3 blocks/CU).
  gemm_bt<1, 1, 128><<<dim3(256, 1, 4), 256, 0, stream>>>(
      Q, Kb, P, nullptr, lsum, 2048, 2048, 1024,
      (size_t)2097152, (size_t)2097152, (size_t)4194304);
  // 6) out = (P~ V) / lsum[row].  TM=128, 4x4-ish super-tile per XCD.
  gemm_bt<2, 2, 128><<<dim3(128, 1, 4), 256, 0, stream>>>(
      P, Vt, out, nullptr, lsum, 2048, 1024, 2048,
      (size_t)4194304, (size_t)2097152, (size_t)2097152);
}

// Round 7
// 245.059 us; speedup vs baseline: 1.0333x; 1.0333x over previous
//
#include <hip/hip_runtime.h>
#include <hip/hip_bf16.h>
#include <stdint.h>

typedef unsigned short u16;
typedef __attribute__((ext_vector_type(8))) short short8;   // 8 x bf16 (4 VGPRs) MFMA A/B frag
typedef __attribute__((ext_vector_type(4))) float floatx4;  // MFMA C/D frag

#define BATCH 4
#define SEQ   2048
#define DIM   1024

__device__ inline u16 f2bf(float f) {
  union { float f; uint32_t u; } v; v.f = f;
  uint32_t r = v.u + 0x7fffu + ((v.u >> 16) & 1u);  // RNE
  return (u16)(r >> 16);
}

// async global->LDS, 16B per lane; LDS dest is wave-uniform base (+lane*16 by HW)
__device__ inline void gload_lds16(const u16* g, u16* l) {
  __builtin_amdgcn_global_load_lds((const __attribute__((address_space(1))) uint32_t*)g,
                                   (__attribute__((address_space(3))) uint32_t*)l,
                                   16, 0, 0);
}

// ---------------- elementwise fp32 -> bf16 (+ zero the rowsum buffer) ----------------
__global__ __launch_bounds__(256) void cvt_x(const float* __restrict__ in,
                                             u16* __restrict__ out,
                                             float* __restrict__ lsum) {
  size_t i = ((size_t)blockIdx.x * 256 + threadIdx.x) * 4;
  float4 v = *(const float4*)(in + i);
  ushort4 o;
  o.x = f2bf(v.x); o.y = f2bf(v.y); o.z = f2bf(v.z); o.w = f2bf(v.w);
  *(ushort4*)(out + i) = o;
  if (blockIdx.x < 8) {  // zero 8192 floats of lsum
    float4 z = {0.f, 0.f, 0.f, 0.f};
    *(float4*)(lsum + (size_t)blockIdx.x * 1024 + threadIdx.x * 4) = z;
  }
}

// ---------------- W[d][h] fp32 -> Wt[h][d] bf16 (3 weights via z) + bias gather ----------------
__global__ __launch_bounds__(256) void transpose_w(const float* __restrict__ Wq,
                                                   const float* __restrict__ Wk,
                                                   const float* __restrict__ Wv,
                                                   const float* __restrict__ bq,
                                                   const float* __restrict__ bk,
                                                   const float* __restrict__ bv,
                                                   u16* __restrict__ out,
                                                   float* __restrict__ bias) {
  const float* W = (blockIdx.z == 0) ? Wq : (blockIdx.z == 1) ? Wk : Wv;
  u16* o = out + (size_t)blockIdx.z * (1u << 20);
  if (blockIdx.x == 0 && blockIdx.y == 0) {  // pack biases contiguously (fused launch)
    const float* bsrc = (blockIdx.z == 0) ? bq : (blockIdx.z == 1) ? bk : bv;
    float4 b4 = *(const float4*)(bsrc + threadIdx.x * 4);
    *(float4*)(bias + blockIdx.z * 1024 + threadIdx.x * 4) = b4;
  }
  __shared__ u16 tile[32][33];
  int c0 = blockIdx.x * 32, r0 = blockIdx.y * 32;
  int tx = threadIdx.x & 31, ty = threadIdx.x >> 5;  // ty 0..7
#pragma unroll
  for (int p = 0; p < 4; ++p)
    tile[p * 8 + ty][tx] = f2bf(W[(size_t)(r0 + p * 8 + ty) * DIM + c0 + tx]);
  __syncthreads();
#pragma unroll
  for (int p = 0; p < 4; ++p)
    o[(size_t)(c0 + p * 8 + ty) * DIM + r0 + tx] = tile[tx][p * 8 + ty];
}

// ---------------- bf16 GEMM, BK=64 (two 32-k slabs per barrier pair) ----------------
// C[m][n] = sum_k A[m][k] * Bt[n][k].  Block tile TM x 128.
// TM=128: 4 waves of 64x64 (acc 4x4), 3 blocks/CU.
// TM=256: 4 waves of 128x64 (acc 8x4), 2 blocks/CU.  Real-run (L2-warm) winner for
//   QK^T (~36 us vs ~47 by cross-round arithmetic); profiled replay shows ~74 us
//   because rocprof flushes L2 — trust end-to-end dur, not the cold-replay counter.
// EPI 0: (acc+bias[col])*zscale (z==0 -> 1/32), bf16 out.
// EPI 1: exp(acc), bf16 out, atomicAdd per-row sums into lsum.
// EPI 2: acc * (1/lsum[row]), fp32 out.
// EPI 3: acc + bias[row] (V bias), bf16, column-demuxed store into Vt[b][h][s].
// SWIZ 0: grid(M/TM,8,z): mt=x, nt=y   (xcd = mt%8 -> A-stripe per XCD)
// SWIZ 1: grid(256,1,z): mt 16, nt 16  (4m x 8n super-tile per XCD, TM=128)
// SWIZ 2: grid(128,1,z): mt 16, nt 8   (4m x 4n super-tile per XCD, TM=128)
// SWIZ 3: grid(64,8,1): nt=x, mt=y     (xcd = nt%8 -> B-stripe per XCD)
// SWIZ 4: grid(128,1,z): mt 8, nt 16   (TM=256: 4m x 4n per XCD)
template <int EPI, int SWIZ, int TM>
__global__ __launch_bounds__(256, (TM == 256) ? 2 : 3)
void gemm_bt(const u16* __restrict__ A, const u16* __restrict__ Bt,
             void* __restrict__ Cv, const float* __restrict__ bias,
             float* __restrict__ lsum, int M, int N, int K,
             size_t sA, size_t sB, size_t sC) {
  constexpr int MI = TM / 32;          // acc rows of 16 per wave (4 or 8)
  constexpr int AS = TM / 64;          // A staging insts per wave per slab (2 or 4)
  __shared__ u16 ldsA[TM * 64];        // two slabs of TM x 32
  __shared__ u16 ldsB[128 * 64];
  const int lane = threadIdx.x & 63;
  const int wave = threadIdx.x >> 6;

  int mt, nt;
  if (SWIZ == 0) {
    mt = blockIdx.x; nt = blockIdx.y;
  } else if (SWIZ == 1) {
    const int lin = blockIdx.x;            // 0..255
    const int c = lin & 7, j = lin >> 3;   // xcd-slot, index within slot
    mt = 4 * (c & 3) + (j & 3);            // 16 m-tiles
    nt = 8 * (c >> 2) + (j >> 2);          // 16 n-tiles
  } else if (SWIZ == 2) {
    const int lin = blockIdx.x;            // 0..127
    const int c = lin & 7, j = lin >> 3;
    mt = 4 * (c >> 1) + (j & 3);           // 16 m-tiles
    nt = 4 * (c & 1) + (j >> 2);           // 8 n-tiles
  } else if (SWIZ == 3) {
    nt = blockIdx.x; mt = blockIdx.y;
  } else {
    const int lin = blockIdx.x;            // 0..127
    const int c = lin & 7, j = lin >> 3;
    mt = 4 * (c & 1) + (j & 3);            // 8 m-tiles
    nt = 4 * (c >> 1) + (j >> 2);          // 16 n-tiles
  }

  const u16* Ab = A + sA * blockIdx.z + (size_t)mt * TM * K;
  const u16* Bb = Bt + sB * blockIdx.z + (size_t)nt * 128 * K;

  // staging: wave w covers A rows [w*TM/4,...), B rows [w*32,...); insts of 16 rows.
  const int sr = lane >> 2;          // row within 16-row group
  const int sc = (lane & 3) * 8;     // k-offset (elements), 16B chunks
  const u16* gA0 = Ab + (size_t)(wave * (TM / 4) + sr) * K + sc;
  const u16* gB0 = Bb + (size_t)(wave * 32 + sr) * K + sc;
  u16* lA0 = ldsA + wave * (TM / 4) * 32;   // per 16-row inst: +512 els
  u16* lB0 = ldsB + wave * 1024;
  constexpr int SLA = TM * 32;       // A slab1 offset (elements)
  constexpr int SLB = 4096;          // B slab1 offset

  // compute: waves 2x2; wave tile (TM/2) x 64
  const int wm = (wave >> 1) * (TM / 2);
  const int wn = (wave & 1) * 64;
  const int fr = lane & 15;
  const int fk = (lane >> 4) * 8;
  const u16* la = ldsA + (wm + fr) * 32 + fk;
  const u16* lb = ldsB + (wn + fr) * 32 + fk;

  floatx4 acc[MI][4] = {};

  for (int kt = 0; kt < K; kt += 64) {
    __syncthreads();
#pragma unroll
    for (int i = 0; i < AS; ++i) {
      gload_lds16(gA0 + kt + (size_t)(16 * i) * K, lA0 + i * 512);
      gload_lds16(gA0 + kt + 32 + (size_t)(16 * i) * K, lA0 + SLA + i * 512);
    }
#pragma unroll
    for (int i = 0; i < 2; ++i) {
      gload_lds16(gB0 + kt + (size_t)(16 * i) * K, lB0 + i * 512);
      gload_lds16(gB0 + kt + 32 + (size_t)(16 * i) * K, lB0 + SLB + i * 512);
    }
    __syncthreads();
#pragma unroll
    for (int ks = 0; ks < 2; ++ks) {
      short8 a[MI], b[4];
#pragma unroll
      for (int i = 0; i < MI; ++i)
        a[i] = *(const short8*)(la + ks * SLA + i * 512);
#pragma unroll
      for (int i = 0; i < 4; ++i)
        b[i] = *(const short8*)(lb + ks * SLB + i * 512);
#pragma unroll
      for (int mi = 0; mi < MI; ++mi)
#pragma unroll
        for (int ni = 0; ni < 4; ++ni)
          acc[mi][ni] = __builtin_amdgcn_mfma_f32_16x16x32_bf16(a[mi], b[ni], acc[mi][ni], 0, 0, 0);
    }
  }

  // epilogue: C/D layout col=lane&15, row=(lane>>4)*4+r
  const int er = (lane >> 4) * 4;
  const int ec = lane & 15;
  const int r0 = mt * TM + wm;
  const int c0 = nt * 128 + wn;

  if (EPI == 0) {
    u16* C = (u16*)Cv + sC * blockIdx.z;
    const float* bz = bias + blockIdx.z * 1024;
    const float zs = (blockIdx.z == 0) ? 0.03125f : 1.0f;  // fold 1/sqrt(1024) into Q
#pragma unroll
    for (int mi = 0; mi < MI; ++mi)
#pragma unroll
      for (int ni = 0; ni < 4; ++ni) {
        const int col = c0 + ni * 16 + ec;
        const float bb = bz[col];
#pragma unroll
        for (int r = 0; r < 4; ++r) {
          const int row = r0 + mi * 16 + er + r;
          C[(size_t)row * N + col] = f2bf((acc[mi][ni][r] + bb) * zs);
        }
      }
  } else if (EPI == 1) {
    // P~ = exp(s) (no max subtraction: |s| bounded, fp32-safe), row sums -> lsum.
    u16* C = (u16*)Cv + sC * blockIdx.z;
    float* lz = lsum + blockIdx.z * 2048;
#pragma unroll
    for (int mi = 0; mi < MI; ++mi) {
      float rs[4] = {0.f, 0.f, 0.f, 0.f};
#pragma unroll
      for (int ni = 0; ni < 4; ++ni) {
        const int col = c0 + ni * 16 + ec;
#pragma unroll
        for (int r = 0; r < 4; ++r) {
          const int row = r0 + mi * 16 + er + r;
          const float e = exp2f(acc[mi][ni][r] * 1.44269504088896340736f);
          C[(size_t)row * N + col] = f2bf(e);
          rs[r] += e;
        }
      }
#pragma unroll
      for (int o = 1; o < 16; o <<= 1)
#pragma unroll
        for (int r = 0; r < 4; ++r) rs[r] += __shfl_xor(rs[r], o);
      if ((lane & 15) == 0) {
#pragma unroll
        for (int r = 0; r < 4; ++r)
          atomicAdd(&lz[r0 + mi * 16 + er + r], rs[r]);
      }
    }
  } else if (EPI == 2) {
    float* C = (float*)Cv + sC * blockIdx.z;
    const float* lz = lsum + blockIdx.z * 2048;
#pragma unroll
    for (int mi = 0; mi < MI; ++mi) {
      float inv[4];
#pragma unroll
      for (int r = 0; r < 4; ++r) inv[r] = 1.0f / lz[r0 + mi * 16 + er + r];
#pragma unroll
      for (int ni = 0; ni < 4; ++ni) {
        const int col = c0 + ni * 16 + ec;
#pragma unroll
        for (int r = 0; r < 4; ++r) {
          const int row = r0 + mi * 16 + er + r;
          C[(size_t)row * N + col] = acc[mi][ni][r] * inv[r];
        }
      }
    }
  } else {
    // Vt[b][h][s]: rows m = h, cols n = global s (b = col>>11).
    u16* C = (u16*)Cv;
    const float* bz = bias + 2 * 1024;  // bv, indexed by row (=h)
#pragma unroll
    for (int mi = 0; mi < MI; ++mi) {
      float bb[4];
#pragma unroll
      for (int r = 0; r < 4; ++r) bb[r] = bz[r0 + mi * 16 + er + r];
#pragma unroll
      for (int ni = 0; ni < 4; ++ni) {
        const int col = c0 + ni * 16 + ec;
        const size_t base = (size_t)(col >> 11) * (1u << 21) + (col & 2047);
#pragma unroll
        for (int r = 0; r < 4; ++r) {
          const int row = r0 + mi * 16 + er + r;
          C[base + (size_t)row * 2048] = f2bf(acc[mi][ni][r] + bb[r]);
        }
      }
    }
  }
}

extern "C" void kernel_launch(void* const* d_in, const int* in_sizes, int n_in,
                              void* d_out, int out_size, void* d_ws, size_t ws_size,
                              hipStream_t stream) {
  const float* x  = (const float*)d_in[0];
  const float* Wq = (const float*)d_in[1];
  const float* bq = (const float*)d_in[2];
  const float* Wk = (const float*)d_in[3];
  const float* bk = (const float*)d_in[4];
  const float* Wv = (const float*)d_in[5];
  const float* bv = (const float*)d_in[6];
  float* out = (float*)d_out;

  char* ws = (char*)d_ws;
  const size_t MB = 1ull << 20;
  u16* Q    = (u16*)(ws + 0 * MB);    // [2][8192][1024] bf16: Q,K contiguous
  u16* Kb   = (u16*)(ws + 16 * MB);
  u16* Vt   = (u16*)(ws + 48 * MB);   // [4][1024][2048]
  u16* Xb   = (u16*)(ws + 64 * MB);   // [8192][1024]
  u16* Wt   = (u16*)(ws + 80 * MB);   // [3][1024][1024]
  float* bias = (float*)(ws + 86 * MB);  // [3][1024]
  float* lsum = (float*)(ws + 87 * MB);  // [4][2048] softmax denominators
  u16* P    = (u16*)(ws + 88 * MB);   // [4][2048][2048] exp(scores), ends 120MB
  (void)Kb; (void)ws_size; (void)in_sizes; (void)n_in; (void)out_size;

  // 1) x -> bf16 (+ zero lsum)
  cvt_x<<<8192, 256, 0, stream>>>(x, Xb, lsum);
  // 2) W -> Wt bf16 (+ bias gather fused)
  transpose_w<<<dim3(32, 32, 3), 256, 0, stream>>>(Wq, Wk, Wv, bq, bk, bv, Wt, bias);
  // 3) Q,K projection (Q pre-scaled by 1/32), z = q/k.  TM=128 (best real-run), A-stripe per XCD.
  gemm_bt<0, 0, 128><<<dim3(64, 8, 2), 256, 0, stream>>>(
      Xb, Wt, Q, bias, nullptr, 8192, 1024, 1024,
      (size_t)0, (size_t)(1u << 20), (size_t)(8u << 20));
  // 4) Vt = Wv^T x^T + bv (direct transposed V projection).  TM=128, B-stripe per XCD.
  gemm_bt<3, 3, 128><<<dim3(64, 8, 1), 256, 0, stream>>>(
      Wt + 2 * (1u << 20), Xb, Vt, bias, nullptr, 1024, 8192, 1024,
      (size_t)0, (size_t)0, (size_t)0);
  // 5) P~ = exp(Q K^T), row sums -> lsum.  TM=256 (best real-run; inputs L2-warm), 4x4 per XCD.
  gemm_bt<1, 4, 256><<<dim3(128, 1, 4), 256, 0, stream>>>(
      Q, Kb, P, nullptr, lsum, 2048, 2048, 1024,
      (size_t)2097152, (size_t)2097152, (size_t)4194304);
  // 6) out = (P~ V) / lsum[row].  TM=128, 4x4-ish super-tile per XCD.
  gemm_bt<2, 2, 128><<<dim3(128, 1, 4), 256, 0, stream>>>(
      P, Vt, out, nullptr, lsum, 2048, 1024, 2048,
      (size_t)4194304, (size_t)2097152, (size_t)2097152);
}

// Round 8
// 237.963 us; speedup vs baseline: 1.0641x; 1.0298x over previous
//
#include <hip/hip_runtime.h>
#include <hip/hip_bf16.h>
#include <stdint.h>

typedef unsigned short u16;
typedef __attribute__((ext_vector_type(8))) short short8;   // 8 x bf16 (4 VGPRs) MFMA A/B frag
typedef __attribute__((ext_vector_type(4))) float floatx4;  // MFMA C/D frag

#define BATCH 4
#define SEQ   2048
#define DIM   1024

__device__ inline u16 f2bf(float f) {
  union { float f; uint32_t u; } v; v.f = f;
  uint32_t r = v.u + 0x7fffu + ((v.u >> 16) & 1u);  // RNE
  return (u16)(r >> 16);
}

// packed fp32x2 -> bf16x2 (v_cvt_pk_bf16_f32 on gfx950), RNE — bit-identical to f2bf
__device__ inline uint32_t f2bf2(float lo, float hi) {
  __hip_bfloat162 h = __float22bfloat162_rn(float2{lo, hi});
  union { __hip_bfloat162 h; uint32_t u; } v; v.h = h;
  return v.u;
}

// async global->LDS, 16B per lane; LDS dest is wave-uniform base (+lane*16 by HW)
__device__ inline void gload_lds16(const u16* g, u16* l) {
  __builtin_amdgcn_global_load_lds((const __attribute__((address_space(1))) uint32_t*)g,
                                   (__attribute__((address_space(3))) uint32_t*)l,
                                   16, 0, 0);
}

// ---------------- elementwise fp32 -> bf16 (+ zero the rowsum buffer) ----------------
__global__ __launch_bounds__(256) void cvt_x(const float* __restrict__ in,
                                             u16* __restrict__ out,
                                             float* __restrict__ lsum) {
  size_t i = ((size_t)blockIdx.x * 256 + threadIdx.x) * 4;
  float4 v = *(const float4*)(in + i);
  uint2 o;
  o.x = f2bf2(v.x, v.y);
  o.y = f2bf2(v.z, v.w);
  *(uint2*)(out + i) = o;
  if (blockIdx.x < 8) {  // zero 8192 floats of lsum
    float4 z = {0.f, 0.f, 0.f, 0.f};
    *(float4*)(lsum + (size_t)blockIdx.x * 1024 + threadIdx.x * 4) = z;
  }
}

// ---------------- W[d][h] fp32 -> Wt[h][d] bf16 (3 weights via z) + bias gather ----------------
__global__ __launch_bounds__(256) void transpose_w(const float* __restrict__ Wq,
                                                   const float* __restrict__ Wk,
                                                   const float* __restrict__ Wv,
                                                   const float* __restrict__ bq,
                                                   const float* __restrict__ bk,
                                                   const float* __restrict__ bv,
                                                   u16* __restrict__ out,
                                                   float* __restrict__ bias) {
  const float* W = (blockIdx.z == 0) ? Wq : (blockIdx.z == 1) ? Wk : Wv;
  u16* o = out + (size_t)blockIdx.z * (1u << 20);
  if (blockIdx.x == 0 && blockIdx.y == 0) {  // pack biases contiguously (fused launch)
    const float* bsrc = (blockIdx.z == 0) ? bq : (blockIdx.z == 1) ? bk : bv;
    float4 b4 = *(const float4*)(bsrc + threadIdx.x * 4);
    *(float4*)(bias + blockIdx.z * 1024 + threadIdx.x * 4) = b4;
  }
  __shared__ u16 tile[32][33];
  int c0 = blockIdx.x * 32, r0 = blockIdx.y * 32;
  int tx = threadIdx.x & 31, ty = threadIdx.x >> 5;  // ty 0..7
#pragma unroll
  for (int p = 0; p < 4; ++p)
    tile[p * 8 + ty][tx] = f2bf(W[(size_t)(r0 + p * 8 + ty) * DIM + c0 + tx]);
  __syncthreads();
#pragma unroll
  for (int p = 0; p < 4; ++p)
    o[(size_t)(c0 + p * 8 + ty) * DIM + r0 + tx] = tile[tx][p * 8 + ty];
}

// ---------------- bf16 GEMM, BK=64 (two 32-k slabs per barrier pair) ----------------
// C[m][n] = sum_k A[m][k] * Bt[n][k].  Block tile TM x 128.
// Config locked to best END-TO-END measurement (R5=238us): QKV TM256, QKT TM256,
// Vt/PV TM128.  Per-dispatch profiled durations are unreliable here (same QKT-TM256
// dispatch profiled 74us in one run, 48us in another — replay cache artifact).
// EPI 0: (acc+bias[col])*zscale (z==0 -> 1/32), bf16 out.
// EPI 1: exp(acc), bf16 out, atomicAdd per-row sums into lsum.
// EPI 2: acc * (1/lsum[row]), fp32 out.
// EPI 3: acc + bias[row] (V bias), bf16, column-demuxed store into Vt[b][h][s].
// SWIZ 0: grid(M/TM,8,z): mt=x, nt=y   (xcd = mt%8 -> A-stripe per XCD)
// SWIZ 1: grid(256,1,z): mt 16, nt 16  (4m x 8n super-tile per XCD, TM=128)
// SWIZ 2: grid(128,1,z): mt 16, nt 8   (4m x 4n super-tile per XCD, TM=128)
// SWIZ 3: grid(64,8,1): nt=x, mt=y     (xcd = nt%8 -> B-stripe per XCD)
// SWIZ 4: grid(128,1,z): mt 8, nt 16   (TM=256: 4m x 4n per XCD)
template <int EPI, int SWIZ, int TM>
__global__ __launch_bounds__(256, (TM == 256) ? 2 : 3)
void gemm_bt(const u16* __restrict__ A, const u16* __restrict__ Bt,
             void* __restrict__ Cv, const float* __restrict__ bias,
             float* __restrict__ lsum, int M, int N, int K,
             size_t sA, size_t sB, size_t sC) {
  constexpr int MI = TM / 32;          // acc rows of 16 per wave (4 or 8)
  constexpr int AS = TM / 64;          // A staging insts per wave per slab (2 or 4)
  __shared__ u16 ldsA[TM * 64];        // two slabs of TM x 32
  __shared__ u16 ldsB[128 * 64];
  const int lane = threadIdx.x & 63;
  const int wave = threadIdx.x >> 6;

  int mt, nt;
  if (SWIZ == 0) {
    mt = blockIdx.x; nt = blockIdx.y;
  } else if (SWIZ == 1) {
    const int lin = blockIdx.x;            // 0..255
    const int c = lin & 7, j = lin >> 3;   // xcd-slot, index within slot
    mt = 4 * (c & 3) + (j & 3);            // 16 m-tiles
    nt = 8 * (c >> 2) + (j >> 2);          // 16 n-tiles
  } else if (SWIZ == 2) {
    const int lin = blockIdx.x;            // 0..127
    const int c = lin & 7, j = lin >> 3;
    mt = 4 * (c >> 1) + (j & 3);           // 16 m-tiles
    nt = 4 * (c & 1) + (j >> 2);           // 8 n-tiles
  } else if (SWIZ == 3) {
    nt = blockIdx.x; mt = blockIdx.y;
  } else {
    const int lin = blockIdx.x;            // 0..127
    const int c = lin & 7, j = lin >> 3;
    mt = 4 * (c & 1) + (j & 3);            // 8 m-tiles
    nt = 4 * (c >> 1) + (j >> 2);          // 16 n-tiles
  }

  const u16* Ab = A + sA * blockIdx.z + (size_t)mt * TM * K;
  const u16* Bb = Bt + sB * blockIdx.z + (size_t)nt * 128 * K;

  // staging: wave w covers A rows [w*TM/4,...), B rows [w*32,...); insts of 16 rows.
  const int sr = lane >> 2;          // row within 16-row group
  const int sc = (lane & 3) * 8;     // k-offset (elements), 16B chunks
  const u16* gA0 = Ab + (size_t)(wave * (TM / 4) + sr) * K + sc;
  const u16* gB0 = Bb + (size_t)(wave * 32 + sr) * K + sc;
  u16* lA0 = ldsA + wave * (TM / 4) * 32;   // per 16-row inst: +512 els
  u16* lB0 = ldsB + wave * 1024;
  constexpr int SLA = TM * 32;       // A slab1 offset (elements)
  constexpr int SLB = 4096;          // B slab1 offset

  // compute: waves 2x2; wave tile (TM/2) x 64
  const int wm = (wave >> 1) * (TM / 2);
  const int wn = (wave & 1) * 64;
  const int fr = lane & 15;
  const int fk = (lane >> 4) * 8;
  const u16* la = ldsA + (wm + fr) * 32 + fk;
  const u16* lb = ldsB + (wn + fr) * 32 + fk;

  floatx4 acc[MI][4] = {};

  for (int kt = 0; kt < K; kt += 64) {
    __syncthreads();
#pragma unroll
    for (int i = 0; i < AS; ++i) {
      gload_lds16(gA0 + kt + (size_t)(16 * i) * K, lA0 + i * 512);
      gload_lds16(gA0 + kt + 32 + (size_t)(16 * i) * K, lA0 + SLA + i * 512);
    }
#pragma unroll
    for (int i = 0; i < 2; ++i) {
      gload_lds16(gB0 + kt + (size_t)(16 * i) * K, lB0 + i * 512);
      gload_lds16(gB0 + kt + 32 + (size_t)(16 * i) * K, lB0 + SLB + i * 512);
    }
    __syncthreads();
#pragma unroll
    for (int ks = 0; ks < 2; ++ks) {
      short8 a[MI], b[4];
#pragma unroll
      for (int i = 0; i < MI; ++i)
        a[i] = *(const short8*)(la + ks * SLA + i * 512);
#pragma unroll
      for (int i = 0; i < 4; ++i)
        b[i] = *(const short8*)(lb + ks * SLB + i * 512);
#pragma unroll
      for (int mi = 0; mi < MI; ++mi)
#pragma unroll
        for (int ni = 0; ni < 4; ++ni)
          acc[mi][ni] = __builtin_amdgcn_mfma_f32_16x16x32_bf16(a[mi], b[ni], acc[mi][ni], 0, 0, 0);
    }
  }

  // epilogue: C/D layout col=lane&15, row=(lane>>4)*4+r
  const int er = (lane >> 4) * 4;
  const int ec = lane & 15;
  const int r0 = mt * TM + wm;
  const int c0 = nt * 128 + wn;

  if (EPI == 0) {
    u16* C = (u16*)Cv + sC * blockIdx.z;
    const float* bz = bias + blockIdx.z * 1024;
    const float zs = (blockIdx.z == 0) ? 0.03125f : 1.0f;  // fold 1/sqrt(1024) into Q
#pragma unroll
    for (int mi = 0; mi < MI; ++mi)
#pragma unroll
      for (int ni = 0; ni < 4; ++ni) {
        const int col = c0 + ni * 16 + ec;
        const float bb = bz[col];
        const int row = r0 + mi * 16 + er;
        const uint32_t p0 = f2bf2((acc[mi][ni][0] + bb) * zs, (acc[mi][ni][1] + bb) * zs);
        const uint32_t p1 = f2bf2((acc[mi][ni][2] + bb) * zs, (acc[mi][ni][3] + bb) * zs);
        C[(size_t)(row + 0) * N + col] = (u16)p0;
        C[(size_t)(row + 1) * N + col] = (u16)(p0 >> 16);
        C[(size_t)(row + 2) * N + col] = (u16)p1;
        C[(size_t)(row + 3) * N + col] = (u16)(p1 >> 16);
      }
  } else if (EPI == 1) {
    // P~ = exp(s) (no max subtraction: |s| bounded, fp32-safe), row sums -> lsum.
    u16* C = (u16*)Cv + sC * blockIdx.z;
    float* lz = lsum + blockIdx.z * 2048;
#pragma unroll
    for (int mi = 0; mi < MI; ++mi) {
      float rs[4] = {0.f, 0.f, 0.f, 0.f};
#pragma unroll
      for (int ni = 0; ni < 4; ++ni) {
        const int col = c0 + ni * 16 + ec;
        const int row = r0 + mi * 16 + er;
        float e[4];
#pragma unroll
        for (int r = 0; r < 4; ++r) {
          e[r] = exp2f(acc[mi][ni][r] * 1.44269504088896340736f);
          rs[r] += e[r];
        }
        const uint32_t p0 = f2bf2(e[0], e[1]);
        const uint32_t p1 = f2bf2(e[2], e[3]);
        C[(size_t)(row + 0) * N + col] = (u16)p0;
        C[(size_t)(row + 1) * N + col] = (u16)(p0 >> 16);
        C[(size_t)(row + 2) * N + col] = (u16)p1;
        C[(size_t)(row + 3) * N + col] = (u16)(p1 >> 16);
      }
#pragma unroll
      for (int o = 1; o < 16; o <<= 1)
#pragma unroll
        for (int r = 0; r < 4; ++r) rs[r] += __shfl_xor(rs[r], o);
      if ((lane & 15) == 0) {
#pragma unroll
        for (int r = 0; r < 4; ++r)
          atomicAdd(&lz[r0 + mi * 16 + er + r], rs[r]);
      }
    }
  } else if (EPI == 2) {
    float* C = (float*)Cv + sC * blockIdx.z;
    const float* lz = lsum + blockIdx.z * 2048;
#pragma unroll
    for (int mi = 0; mi < MI; ++mi) {
      float inv[4];
#pragma unroll
      for (int r = 0; r < 4; ++r) inv[r] = 1.0f / lz[r0 + mi * 16 + er + r];
#pragma unroll
      for (int ni = 0; ni < 4; ++ni) {
        const int col = c0 + ni * 16 + ec;
#pragma unroll
        for (int r = 0; r < 4; ++r) {
          const int row = r0 + mi * 16 + er + r;
          C[(size_t)row * N + col] = acc[mi][ni][r] * inv[r];
        }
      }
    }
  } else {
    // Vt[b][h][s]: rows m = h, cols n = global s (b = col>>11).
    u16* C = (u16*)Cv;
    const float* bz = bias + 2 * 1024;  // bv, indexed by row (=h)
#pragma unroll
    for (int mi = 0; mi < MI; ++mi) {
      float bb[4];
#pragma unroll
      for (int r = 0; r < 4; ++r) bb[r] = bz[r0 + mi * 16 + er + r];
#pragma unroll
      for (int ni = 0; ni < 4; ++ni) {
        const int col = c0 + ni * 16 + ec;
        const size_t base = (size_t)(col >> 11) * (1u << 21) + (col & 2047);
        const int row = r0 + mi * 16 + er;
        const uint32_t p0 = f2bf2(acc[mi][ni][0] + bb[0], acc[mi][ni][1] + bb[1]);
        const uint32_t p1 = f2bf2(acc[mi][ni][2] + bb[2], acc[mi][ni][3] + bb[3]);
        C[base + (size_t)(row + 0) * 2048] = (u16)p0;
        C[base + (size_t)(row + 1) * 2048] = (u16)(p0 >> 16);
        C[base + (size_t)(row + 2) * 2048] = (u16)p1;
        C[base + (size_t)(row + 3) * 2048] = (u16)(p1 >> 16);
      }
    }
  }
}

extern "C" void kernel_launch(void* const* d_in, const int* in_sizes, int n_in,
                              void* d_out, int out_size, void* d_ws, size_t ws_size,
                              hipStream_t stream) {
  const float* x  = (const float*)d_in[0];
  const float* Wq = (const float*)d_in[1];
  const float* bq = (const float*)d_in[2];
  const float* Wk = (const float*)d_in[3];
  const float* bk = (const float*)d_in[4];
  const float* Wv = (const float*)d_in[5];
  const float* bv = (const float*)d_in[6];
  float* out = (float*)d_out;

  char* ws = (char*)d_ws;
  const size_t MB = 1ull << 20;
  u16* Q    = (u16*)(ws + 0 * MB);    // [2][8192][1024] bf16: Q,K contiguous
  u16* Kb   = (u16*)(ws + 16 * MB);
  u16* Vt   = (u16*)(ws + 48 * MB);   // [4][1024][2048]
  u16* Xb   = (u16*)(ws + 64 * MB);   // [8192][1024]
  u16* Wt   = (u16*)(ws + 80 * MB);   // [3][1024][1024]
  float* bias = (float*)(ws + 86 * MB);  // [3][1024]
  float* lsum = (float*)(ws + 87 * MB);  // [4][2048] softmax denominators
  u16* P    = (u16*)(ws + 88 * MB);   // [4][2048][2048] exp(scores), ends 120MB
  (void)Kb; (void)ws_size; (void)in_sizes; (void)n_in; (void)out_size;

  // 1) x -> bf16 (+ zero lsum)
  cvt_x<<<8192, 256, 0, stream>>>(x, Xb, lsum);
  // 2) W -> Wt bf16 (+ bias gather fused)
  transpose_w<<<dim3(32, 32, 3), 256, 0, stream>>>(Wq, Wk, Wv, bq, bk, bv, Wt, bias);
  // 3) Q,K projection (Q pre-scaled by 1/32), z = q/k.  TM=256 (R5 best end-to-end).
  gemm_bt<0, 0, 256><<<dim3(32, 8, 2), 256, 0, stream>>>(
      Xb, Wt, Q, bias, nullptr, 8192, 1024, 1024,
      (size_t)0, (size_t)(1u << 20), (size_t)(8u << 20));
  // 4) Vt = Wv^T x^T + bv (direct transposed V projection).  TM=128, B-stripe per XCD.
  gemm_bt<3, 3, 128><<<dim3(64, 8, 1), 256, 0, stream>>>(
      Wt + 2 * (1u << 20), Xb, Vt, bias, nullptr, 1024, 8192, 1024,
      (size_t)0, (size_t)0, (size_t)0);
  // 5) P~ = exp(Q K^T), row sums -> lsum.  TM=256 (R5 best end-to-end), 4x4 per XCD.
  gemm_bt<1, 4, 256><<<dim3(128, 1, 4), 256, 0, stream>>>(
      Q, Kb, P, nullptr, lsum, 2048, 2048, 1024,
      (size_t)2097152, (size_t)2097152, (size_t)4194304);
  // 6) out = (P~ V) / lsum[row].  TM=128, 4x4-ish super-tile per XCD.
  gemm_bt<2, 2, 128><<<dim3(128, 1, 4), 256, 0, stream>>>(
      P, Vt, out, nullptr, lsum, 2048, 1024, 2048,
      (size_t)4194304, (size_t)2097152, (size_t)2097152);
}

// Round 9
// 234.891 us; speedup vs baseline: 1.0780x; 1.0131x over previous
//
#include <hip/hip_runtime.h>
#include <hip/hip_bf16.h>
#include <stdint.h>

typedef unsigned short u16;
typedef __attribute__((ext_vector_type(8))) short short8;   // 8 x bf16 (4 VGPRs) MFMA A/B frag
typedef __attribute__((ext_vector_type(4))) float floatx4;  // MFMA C/D frag

#define BATCH 4
#define SEQ   2048
#define DIM   1024

__device__ inline u16 f2bf(float f) {
  union { float f; uint32_t u; } v; v.f = f;
  uint32_t r = v.u + 0x7fffu + ((v.u >> 16) & 1u);  // RNE
  return (u16)(r >> 16);
}

// packed fp32x2 -> bf16x2 (v_cvt_pk_bf16_f32 on gfx950), RNE — bit-identical to f2bf
__device__ inline uint32_t f2bf2(float lo, float hi) {
  __hip_bfloat162 h = __float22bfloat162_rn(float2{lo, hi});
  union { __hip_bfloat162 h; uint32_t u; } v; v.h = h;
  return v.u;
}

// async global->LDS, 16B per lane; LDS dest is wave-uniform base (+lane*16 by HW)
__device__ inline void gload_lds16(const u16* g, u16* l) {
  __builtin_amdgcn_global_load_lds((const __attribute__((address_space(1))) uint32_t*)g,
                                   (__attribute__((address_space(3))) uint32_t*)l,
                                   16, 0, 0);
}

// ---------------- fused prep: x->bf16, W->Wt bf16, bias gather, lsum zero ----------------
// blocks [0,8192): cvt x.  blocks [8192,11264): transpose W (32x32 tile each).
__global__ __launch_bounds__(256) void prep(const float* __restrict__ x,
                                            const float* __restrict__ Wq,
                                            const float* __restrict__ Wk,
                                            const float* __restrict__ Wv,
                                            const float* __restrict__ bq,
                                            const float* __restrict__ bk,
                                            const float* __restrict__ bv,
                                            u16* __restrict__ Xb,
                                            u16* __restrict__ Wt,
                                            float* __restrict__ bias,
                                            float* __restrict__ lsum) {
  __shared__ u16 tile[32][33];
  const int bx = blockIdx.x;
  if (bx < 8192) {
    size_t i = ((size_t)bx * 256 + threadIdx.x) * 4;
    float4 v = *(const float4*)(x + i);
    uint2 o;
    o.x = f2bf2(v.x, v.y);
    o.y = f2bf2(v.z, v.w);
    *(uint2*)(Xb + i) = o;
    if (bx < 8) {  // zero 8192 floats of lsum
      float4 z = {0.f, 0.f, 0.f, 0.f};
      *(float4*)(lsum + (size_t)bx * 1024 + threadIdx.x * 4) = z;
    }
    return;
  }
  const int t = bx - 8192;
  const int tz = t >> 10;            // 0..2  (weight index)
  const int bxx = t & 31;            // 32 col-tiles
  const int byy = (t >> 5) & 31;     // 32 row-tiles
  const float* W = (tz == 0) ? Wq : (tz == 1) ? Wk : Wv;
  u16* o = Wt + (size_t)tz * (1u << 20);
  if (bxx == 0 && byy == 0) {  // pack biases contiguously
    const float* bsrc = (tz == 0) ? bq : (tz == 1) ? bk : bv;
    float4 b4 = *(const float4*)(bsrc + threadIdx.x * 4);
    *(float4*)(bias + tz * 1024 + threadIdx.x * 4) = b4;
  }
  int c0 = bxx * 32, r0 = byy * 32;
  int tx = threadIdx.x & 31, ty = threadIdx.x >> 5;  // ty 0..7
#pragma unroll
  for (int p = 0; p < 4; ++p)
    tile[p * 8 + ty][tx] = f2bf(W[(size_t)(r0 + p * 8 + ty) * DIM + c0 + tx]);
  __syncthreads();
#pragma unroll
  for (int p = 0; p < 4; ++p)
    o[(size_t)(c0 + p * 8 + ty) * DIM + r0 + tx] = tile[tx][p * 8 + ty];
}

// ---------------- fused QKV+Vt projection, TM=128, BK=64 ----------------
// grid (64,8,3).  z in {0,1}: Q/K = Xb x Wt[z] + b, bf16 -> Q (+ 1/32 for z=0).
// z==2: Vt[b][h][s] = (Wv^T x^T + bv), column-demuxed store.
__global__ __launch_bounds__(256, 3)
void qkv_fused(const u16* __restrict__ Xb, const u16* __restrict__ Wt,
               u16* __restrict__ Q, u16* __restrict__ Vt,
               const float* __restrict__ bias) {
  constexpr int K = 1024;
  __shared__ u16 ldsA[128 * 64];   // two slabs of 128x32
  __shared__ u16 ldsB[128 * 64];
  const int lane = threadIdx.x & 63;
  const int wave = threadIdx.x >> 6;
  const int z = blockIdx.z;

  int mt, nt, N;
  const u16 *Ab, *Bb;
  if (z < 2) {             // Q/K projection: A = Xb rows, B = Wt[z] rows
    mt = blockIdx.x; nt = blockIdx.y; N = 1024;
    Ab = Xb + (size_t)mt * 128 * K;
    Bb = Wt + (size_t)z * (1u << 20) + (size_t)nt * 128 * K;
  } else {                 // Vt projection: A = Wv^T rows (h), B = Xb rows (s)
    nt = blockIdx.x; mt = blockIdx.y; N = 8192;
    Ab = Wt + (size_t)2 * (1u << 20) + (size_t)mt * 128 * K;
    Bb = Xb + (size_t)nt * 128 * K;
  }

  const int sr = lane >> 2;
  const int sc = (lane & 3) * 8;
  const u16* gA0 = Ab + (size_t)(wave * 32 + sr) * K + sc;
  const u16* gB0 = Bb + (size_t)(wave * 32 + sr) * K + sc;
  u16* lA0 = ldsA + wave * 1024;
  u16* lB0 = ldsB + wave * 1024;
  constexpr int SL = 4096;

  const int wm = (wave >> 1) * 64;
  const int wn = (wave & 1) * 64;
  const int fr = lane & 15;
  const int fk = (lane >> 4) * 8;
  const u16* la = ldsA + (wm + fr) * 32 + fk;
  const u16* lb = ldsB + (wn + fr) * 32 + fk;

  floatx4 acc[4][4] = {};

  for (int kt = 0; kt < K; kt += 64) {
    __syncthreads();
#pragma unroll
    for (int i = 0; i < 2; ++i) {
      gload_lds16(gA0 + kt + (size_t)(16 * i) * K, lA0 + i * 512);
      gload_lds16(gA0 + kt + 32 + (size_t)(16 * i) * K, lA0 + SL + i * 512);
      gload_lds16(gB0 + kt + (size_t)(16 * i) * K, lB0 + i * 512);
      gload_lds16(gB0 + kt + 32 + (size_t)(16 * i) * K, lB0 + SL + i * 512);
    }
    __syncthreads();
#pragma unroll
    for (int ks = 0; ks < 2; ++ks) {
      short8 a[4], b[4];
#pragma unroll
      for (int i = 0; i < 4; ++i) a[i] = *(const short8*)(la + ks * SL + i * 512);
#pragma unroll
      for (int i = 0; i < 4; ++i) b[i] = *(const short8*)(lb + ks * SL + i * 512);
#pragma unroll
      for (int mi = 0; mi < 4; ++mi)
#pragma unroll
        for (int ni = 0; ni < 4; ++ni)
          acc[mi][ni] = __builtin_amdgcn_mfma_f32_16x16x32_bf16(a[mi], b[ni], acc[mi][ni], 0, 0, 0);
    }
  }

  const int er = (lane >> 4) * 4;
  const int ec = lane & 15;
  const int r0 = mt * 128 + wm;
  const int c0 = nt * 128 + wn;

  if (z < 2) {
    u16* C = Q + (size_t)z * (8u << 20);
    const float* bz = bias + z * 1024;
    const float zs = (z == 0) ? 0.03125f : 1.0f;  // fold 1/sqrt(1024) into Q
#pragma unroll
    for (int mi = 0; mi < 4; ++mi)
#pragma unroll
      for (int ni = 0; ni < 4; ++ni) {
        const int col = c0 + ni * 16 + ec;
        const float bb = bz[col];
        const int row = r0 + mi * 16 + er;
        const uint32_t p0 = f2bf2((acc[mi][ni][0] + bb) * zs, (acc[mi][ni][1] + bb) * zs);
        const uint32_t p1 = f2bf2((acc[mi][ni][2] + bb) * zs, (acc[mi][ni][3] + bb) * zs);
        C[(size_t)(row + 0) * N + col] = (u16)p0;
        C[(size_t)(row + 1) * N + col] = (u16)(p0 >> 16);
        C[(size_t)(row + 2) * N + col] = (u16)p1;
        C[(size_t)(row + 3) * N + col] = (u16)(p1 >> 16);
      }
  } else {
    const float* bz = bias + 2 * 1024;  // bv, indexed by row (=h)
#pragma unroll
    for (int mi = 0; mi < 4; ++mi) {
      float bb[4];
#pragma unroll
      for (int r = 0; r < 4; ++r) bb[r] = bz[r0 + mi * 16 + er + r];
#pragma unroll
      for (int ni = 0; ni < 4; ++ni) {
        const int col = c0 + ni * 16 + ec;
        const size_t base = (size_t)(col >> 11) * (1u << 21) + (col & 2047);
        const int row = r0 + mi * 16 + er;
        const uint32_t p0 = f2bf2(acc[mi][ni][0] + bb[0], acc[mi][ni][1] + bb[1]);
        const uint32_t p1 = f2bf2(acc[mi][ni][2] + bb[2], acc[mi][ni][3] + bb[3]);
        Vt[base + (size_t)(row + 0) * 2048] = (u16)p0;
        Vt[base + (size_t)(row + 1) * 2048] = (u16)(p0 >> 16);
        Vt[base + (size_t)(row + 2) * 2048] = (u16)p1;
        Vt[base + (size_t)(row + 3) * 2048] = (u16)(p1 >> 16);
      }
    }
  }
}

// ---------------- bf16 GEMM, BK=64 (two 32-k slabs per barrier pair) ----------------
// C[m][n] = sum_k A[m][k] * Bt[n][k].  Block tile TM x 128.
// EPI 1: exp(acc), bf16 out, atomicAdd per-row sums into lsum.
// EPI 2: acc * (1/lsum[row]), fp32 out.
// SWIZ 2: grid(128,1,z): mt 16, nt 8   (4m x 4n super-tile per XCD, TM=128)
// SWIZ 4: grid(128,1,z): mt 8, nt 16   (TM=256: 4m x 4n per XCD)
template <int EPI, int SWIZ, int TM>
__global__ __launch_bounds__(256, (TM == 256) ? 2 : 3)
void gemm_bt(const u16* __restrict__ A, const u16* __restrict__ Bt,
             void* __restrict__ Cv, float* __restrict__ lsum,
             int M, int N, int K, size_t sA, size_t sB, size_t sC) {
  constexpr int MI = TM / 32;
  constexpr int AS = TM / 64;
  __shared__ u16 ldsA[TM * 64];
  __shared__ u16 ldsB[128 * 64];
  const int lane = threadIdx.x & 63;
  const int wave = threadIdx.x >> 6;

  int mt, nt;
  if (SWIZ == 2) {
    const int lin = blockIdx.x;            // 0..127
    const int c = lin & 7, j = lin >> 3;
    mt = 4 * (c >> 1) + (j & 3);           // 16 m-tiles
    nt = 4 * (c & 1) + (j >> 2);           // 8 n-tiles
  } else {
    const int lin = blockIdx.x;            // 0..127
    const int c = lin & 7, j = lin >> 3;
    mt = 4 * (c & 1) + (j & 3);            // 8 m-tiles
    nt = 4 * (c >> 1) + (j >> 2);          // 16 n-tiles
  }

  const u16* Ab = A + sA * blockIdx.z + (size_t)mt * TM * K;
  const u16* Bb = Bt + sB * blockIdx.z + (size_t)nt * 128 * K;

  const int sr = lane >> 2;
  const int sc = (lane & 3) * 8;
  const u16* gA0 = Ab + (size_t)(wave * (TM / 4) + sr) * K + sc;
  const u16* gB0 = Bb + (size_t)(wave * 32 + sr) * K + sc;
  u16* lA0 = ldsA + wave * (TM / 4) * 32;
  u16* lB0 = ldsB + wave * 1024;
  constexpr int SLA = TM * 32;
  constexpr int SLB = 4096;

  const int wm = (wave >> 1) * (TM / 2);
  const int wn = (wave & 1) * 64;
  const int fr = lane & 15;
  const int fk = (lane >> 4) * 8;
  const u16* la = ldsA + (wm + fr) * 32 + fk;
  const u16* lb = ldsB + (wn + fr) * 32 + fk;

  floatx4 acc[MI][4] = {};

  for (int kt = 0; kt < K; kt += 64) {
    __syncthreads();
#pragma unroll
    for (int i = 0; i < AS; ++i) {
      gload_lds16(gA0 + kt + (size_t)(16 * i) * K, lA0 + i * 512);
      gload_lds16(gA0 + kt + 32 + (size_t)(16 * i) * K, lA0 + SLA + i * 512);
    }
#pragma unroll
    for (int i = 0; i < 2; ++i) {
      gload_lds16(gB0 + kt + (size_t)(16 * i) * K, lB0 + i * 512);
      gload_lds16(gB0 + kt + 32 + (size_t)(16 * i) * K, lB0 + SLB + i * 512);
    }
    __syncthreads();
#pragma unroll
    for (int ks = 0; ks < 2; ++ks) {
      short8 a[MI], b[4];
#pragma unroll
      for (int i = 0; i < MI; ++i)
        a[i] = *(const short8*)(la + ks * SLA + i * 512);
#pragma unroll
      for (int i = 0; i < 4; ++i)
        b[i] = *(const short8*)(lb + ks * SLB + i * 512);
#pragma unroll
      for (int mi = 0; mi < MI; ++mi)
#pragma unroll
        for (int ni = 0; ni < 4; ++ni)
          acc[mi][ni] = __builtin_amdgcn_mfma_f32_16x16x32_bf16(a[mi], b[ni], acc[mi][ni], 0, 0, 0);
    }
  }

  const int er = (lane >> 4) * 4;
  const int ec = lane & 15;
  const int r0 = mt * TM + wm;
  const int c0 = nt * 128 + wn;

  if (EPI == 1) {
    // P~ = exp(s) (no max subtraction: |s| bounded, fp32-safe), row sums -> lsum.
    u16* C = (u16*)Cv + sC * blockIdx.z;
    float* lz = lsum + blockIdx.z * 2048;
#pragma unroll
    for (int mi = 0; mi < MI; ++mi) {
      float rs[4] = {0.f, 0.f, 0.f, 0.f};
#pragma unroll
      for (int ni = 0; ni < 4; ++ni) {
        const int col = c0 + ni * 16 + ec;
        const int row = r0 + mi * 16 + er;
        float e[4];
#pragma unroll
        for (int r = 0; r < 4; ++r) {
          e[r] = exp2f(acc[mi][ni][r] * 1.44269504088896340736f);
          rs[r] += e[r];
        }
        const uint32_t p0 = f2bf2(e[0], e[1]);
        const uint32_t p1 = f2bf2(e[2], e[3]);
        C[(size_t)(row + 0) * N + col] = (u16)p0;
        C[(size_t)(row + 1) * N + col] = (u16)(p0 >> 16);
        C[(size_t)(row + 2) * N + col] = (u16)p1;
        C[(size_t)(row + 3) * N + col] = (u16)(p1 >> 16);
      }
#pragma unroll
      for (int o = 1; o < 16; o <<= 1)
#pragma unroll
        for (int r = 0; r < 4; ++r) rs[r] += __shfl_xor(rs[r], o);
      if ((lane & 15) == 0) {
#pragma unroll
        for (int r = 0; r < 4; ++r)
          atomicAdd(&lz[r0 + mi * 16 + er + r], rs[r]);
      }
    }
  } else {
    float* C = (float*)Cv + sC * blockIdx.z;
    const float* lz = lsum + blockIdx.z * 2048;
#pragma unroll
    for (int mi = 0; mi < MI; ++mi) {
      float inv[4];
#pragma unroll
      for (int r = 0; r < 4; ++r) inv[r] = 1.0f / lz[r0 + mi * 16 + er + r];
#pragma unroll
      for (int ni = 0; ni < 4; ++ni) {
        const int col = c0 + ni * 16 + ec;
#pragma unroll
        for (int r = 0; r < 4; ++r) {
          const int row = r0 + mi * 16 + er + r;
          C[(size_t)row * N + col] = acc[mi][ni][r] * inv[r];
        }
      }
    }
  }
}

extern "C" void kernel_launch(void* const* d_in, const int* in_sizes, int n_in,
                              void* d_out, int out_size, void* d_ws, size_t ws_size,
                              hipStream_t stream) {
  const float* x  = (const float*)d_in[0];
  const float* Wq = (const float*)d_in[1];
  const float* bq = (const float*)d_in[2];
  const float* Wk = (const float*)d_in[3];
  const float* bk = (const float*)d_in[4];
  const float* Wv = (const float*)d_in[5];
  const float* bv = (const float*)d_in[6];
  float* out = (float*)d_out;

  char* ws = (char*)d_ws;
  const size_t MB = 1ull << 20;
  u16* Q    = (u16*)(ws + 0 * MB);    // [2][8192][1024] bf16: Q,K contiguous
  u16* Kb   = (u16*)(ws + 16 * MB);
  u16* Vt   = (u16*)(ws + 48 * MB);   // [4][1024][2048]
  u16* Xb   = (u16*)(ws + 64 * MB);   // [8192][1024]
  u16* Wt   = (u16*)(ws + 80 * MB);   // [3][1024][1024]
  float* bias = (float*)(ws + 86 * MB);  // [3][1024]
  float* lsum = (float*)(ws + 87 * MB);  // [4][2048] softmax denominators
  u16* P    = (u16*)(ws + 88 * MB);   // [4][2048][2048] exp(scores), ends 120MB
  (void)Kb; (void)ws_size; (void)in_sizes; (void)n_in; (void)out_size;

  // 1) fused prep: x->bf16, W->Wt, bias gather, lsum zero
  prep<<<11264, 256, 0, stream>>>(x, Wq, Wk, Wv, bq, bk, bv, Xb, Wt, bias, lsum);
  // 2) fused QKV + Vt projection (Q pre-scaled by 1/32), TM=128
  qkv_fused<<<dim3(64, 8, 3), 256, 0, stream>>>(Xb, Wt, Q, Vt, bias);
  // 3) P~ = exp(Q K^T), row sums -> lsum.  TM=256 (best end-to-end), 4x4 per XCD.
  gemm_bt<1, 4, 256><<<dim3(128, 1, 4), 256, 0, stream>>>(
      Q, Kb, P, lsum, 2048, 2048, 1024,
      (size_t)2097152, (size_t)2097152, (size_t)4194304);
  // 4) out = (P~ V) / lsum[row].  TM=128, 4x4-ish super-tile per XCD.
  gemm_bt<2, 2, 128><<<dim3(128, 1, 4), 256, 0, stream>>>(
      P, Vt, out, lsum, 2048, 1024, 2048,
      (size_t)4194304, (size_t)2097152, (size_t)2097152);
}